// Round 1
// baseline (399.121 us; speedup 1.0000x reference)
//
#include <hip/hip_runtime.h>
#include <hip/hip_bf16.h>
#include <cmath>

// ---------------- problem constants ----------------
#define T_TOKENS 4096   // 2*2048
#define DMODEL   1024
#define HDIM     2048
#define NEXP     8
#define BM 128
#define BN 128
#define BK 64
#define MAXROWS 9216    // 8192 routed rows + worst-case per-expert padding to 128
#define MTILES  (MAXROWS / BM)   // 72

typedef __bf16 bf16;
typedef __bf16 bf16x8 __attribute__((ext_vector_type(8)));
typedef __bf16 bf16x4 __attribute__((ext_vector_type(4)));
typedef float  f32x4  __attribute__((ext_vector_type(4)));

// async global->LDS, 16B per lane (LDS dest must be uniform base + lane*16)
__device__ inline void gload_lds16(const void* g, void* l) {
  __builtin_amdgcn_global_load_lds(
      (const __attribute__((address_space(1))) void*)g,
      (__attribute__((address_space(3))) void*)l, 16, 0, 0);
}

// ---------------- router: logits -> softmax -> top2 -> weights; also x -> bf16 ----------------
__global__ __launch_bounds__(256) void router_kernel(
    const float* __restrict__ x, const float* __restrict__ gw,
    bf16* __restrict__ xb, int* __restrict__ es, float* __restrict__ wsv,
    int* __restrict__ counts)
{
  int wid = threadIdx.x >> 6, lane = threadIdx.x & 63;
  int t = blockIdx.x * 4 + wid;
  if (t >= T_TOKENS) return;
  const float* xrow = x + (size_t)t * DMODEL;

  double acc[NEXP];
#pragma unroll
  for (int e = 0; e < NEXP; e++) acc[e] = 0.0;

#pragma unroll
  for (int i = 0; i < 4; i++) {
    int d0 = (i * 64 + lane) * 4;
    float4 xv = *(const float4*)(xrow + d0);
    bf16x4 o = { (bf16)xv.x, (bf16)xv.y, (bf16)xv.z, (bf16)xv.w };
    *(bf16x4*)(xb + (size_t)t * DMODEL + d0) = o;
    const float* g0 = gw + (size_t)d0 * NEXP;
    float xs[4] = { xv.x, xv.y, xv.z, xv.w };
#pragma unroll
    for (int j = 0; j < 4; j++)
#pragma unroll
      for (int e = 0; e < NEXP; e++)
        acc[e] += (double)xs[j] * (double)g0[j * NEXP + e];
  }
#pragma unroll
  for (int e = 0; e < NEXP; e++) {
    double v = acc[e];
#pragma unroll
    for (int m = 32; m >= 1; m >>= 1) v += __shfl_xor(v, m, 64);
    acc[e] = v;
  }
  if (lane == 0) {
    float l[NEXP], p[NEXP];
    float mx = -1e30f;
#pragma unroll
    for (int e = 0; e < NEXP; e++) { l[e] = (float)acc[e]; mx = fmaxf(mx, l[e]); }
    float s = 0.f;
#pragma unroll
    for (int e = 0; e < NEXP; e++) { p[e] = __expf(l[e] - mx); s += p[e]; }
#pragma unroll
    for (int e = 0; e < NEXP; e++) p[e] /= s;
    int i0 = 0;
#pragma unroll
    for (int e = 1; e < NEXP; e++) if (p[e] > p[i0]) i0 = e;
    int i1 = (i0 == 0) ? 1 : 0;
#pragma unroll
    for (int e = 0; e < NEXP; e++) if (e != i0 && p[e] > p[i1]) i1 = e;
    float wA = p[i0], wB = p[i1];
    float dn = wA + wB + 1e-9f;
    wA /= dn; wB /= dn;
    es[t] = i0; es[T_TOKENS + t] = i1;
    wsv[t] = wA; wsv[T_TOKENS + t] = wB;
    atomicAdd(&counts[i0], 1);
    atomicAdd(&counts[i1], 1);
  }
}

// ---------------- padded prefix offsets, zero cursors ----------------
__global__ void offsets_kernel(const int* __restrict__ counts, int* __restrict__ off,
                               int* __restrict__ cursor)
{
  if (threadIdx.x == 0) {
    int o = 0;
    for (int e = 0; e < NEXP; e++) {
      off[e] = o;
      o += ((counts[e] + BM - 1) / BM) * BM;
    }
    off[NEXP] = o;
  }
  if (threadIdx.x < NEXP) cursor[threadIdx.x] = 0;
}

// ---------------- token -> row assignment ----------------
__global__ void assign_kernel(const int* __restrict__ es, const float* __restrict__ wsv,
                              const int* __restrict__ off, int* __restrict__ cursor,
                              int* __restrict__ perm, float* __restrict__ wt)
{
  int t = blockIdx.x * blockDim.x + threadIdx.x;
  if (t >= T_TOKENS) return;
#pragma unroll
  for (int s = 0; s < 2; s++) {
    int e = es[s * T_TOKENS + t];
    int slot = atomicAdd(&cursor[e], 1);
    int r = off[e] + slot;
    perm[r] = t;
    wt[r] = wsv[s * T_TOKENS + t];
  }
}

// ---------------- weight fp32 [E][R][C] -> bf16 transposed [E][C][R] ----------------
__global__ __launch_bounds__(256) void transpose_cvt_kernel(
    const float* __restrict__ src, bf16* __restrict__ dst, int R, int C)
{
  __shared__ bf16 tile[64][68];
  int e = blockIdx.z;
  int r0 = blockIdx.y * 64, c0 = blockIdx.x * 64;
  const float* s = src + (size_t)e * R * C;
  bf16* d = dst + (size_t)e * R * C;
  int tr = threadIdx.x / 16, tc4 = (threadIdx.x % 16) * 4;
#pragma unroll
  for (int i = 0; i < 4; i++) {
    int r = tr + i * 16;
    float4 v = *(const float4*)(s + (size_t)(r0 + r) * C + c0 + tc4);
    tile[r][tc4 + 0] = (bf16)v.x; tile[r][tc4 + 1] = (bf16)v.y;
    tile[r][tc4 + 2] = (bf16)v.z; tile[r][tc4 + 3] = (bf16)v.w;
  }
  __syncthreads();
#pragma unroll
  for (int i = 0; i < 4; i++) {
    int c = tr + i * 16;   // dst row within tile = source col
    bf16x4 o = { tile[tc4 + 0][c], tile[tc4 + 1][c], tile[tc4 + 2][c], tile[tc4 + 3][c] };
    *(bf16x4*)(d + (size_t)(c0 + c) * R + r0 + tc4) = o;
  }
}

// ---------------- out = bias (broadcast) ----------------
__global__ void out_init_kernel(float* __restrict__ out, const float* __restrict__ bias)
{
  int i = blockIdx.x * blockDim.x + threadIdx.x;
  out[i] = bias[i & (DMODEL - 1)];
}

// ---------------- MFMA GEMM: A[M,K] x W[e][N,K]^T ----------------
// G1 (GELU_STORE=true):  A = xb rows via perm, out -> hidden (gelu, bf16)
// G2 (GELU_STORE=false): A = hidden rows direct, out -> atomicAdd(out[token], wt*acc)
template<int KDIM, int NDIM, bool GELU_STORE>
__global__ __launch_bounds__(256) void moe_gemm_kernel(
    const bf16* __restrict__ A, const bf16* __restrict__ W,
    bf16* __restrict__ hidden, float* __restrict__ out,
    const int* __restrict__ perm, const float* __restrict__ wt,
    const int* __restrict__ off)
{
  int row0 = blockIdx.x * BM;
  int total = off[NEXP];
  if (row0 >= total) return;
  int e = 0;
  while (row0 >= off[e + 1]) e++;
  int n0 = blockIdx.y * BN;
  const bf16* Wb = W + (size_t)e * NDIM * KDIM;

  __shared__ bf16 As[BM * BK];
  __shared__ bf16 Bs[BN * BK];

  int tid = threadIdx.x;
  int lane = tid & 63;
  int wid = tid >> 6;
  int wm = wid >> 1, wn = wid & 1;

  int sr = tid >> 3;            // staging row 0..31 (+ 32*i)
  int sc = (tid & 7) * 8;       // staging col (bf16 elems), 16B per lane

  size_t arow[4];
#pragma unroll
  for (int i = 0; i < 4; i++) {
    int r = sr + i * 32;
    long g;
    if (GELU_STORE) { int p = perm[row0 + r]; g = (p < 0) ? 0 : p; }
    else            { g = row0 + r; }
    arow[i] = (size_t)g * KDIM;
  }
  size_t brow[4];
#pragma unroll
  for (int i = 0; i < 4; i++) brow[i] = (size_t)(n0 + sr + i * 32) * KDIM;

  f32x4 acc[4][4];
#pragma unroll
  for (int m = 0; m < 4; m++)
#pragma unroll
    for (int n = 0; n < 4; n++) acc[m][n] = (f32x4){0.f, 0.f, 0.f, 0.f};

  for (int k0 = 0; k0 < KDIM; k0 += BK) {
#pragma unroll
    for (int i = 0; i < 4; i++)
      gload_lds16(A + arow[i] + k0 + sc, &As[(sr + i * 32) * BK + sc]);
#pragma unroll
    for (int i = 0; i < 4; i++)
      gload_lds16(Wb + brow[i] + k0 + sc, &Bs[(sr + i * 32) * BK + sc]);
    asm volatile("s_waitcnt vmcnt(0)" ::: "memory");
    __syncthreads();

#pragma unroll
    for (int kk = 0; kk < 2; kk++) {
      int klo = kk * 32 + (lane >> 4) * 8;
      bf16x8 af[4], bfr[4];
#pragma unroll
      for (int m = 0; m < 4; m++)
        af[m] = *(const bf16x8*)&As[(wm * 64 + m * 16 + (lane & 15)) * BK + klo];
#pragma unroll
      for (int n = 0; n < 4; n++)
        bfr[n] = *(const bf16x8*)&Bs[(wn * 64 + n * 16 + (lane & 15)) * BK + klo];
#pragma unroll
      for (int m = 0; m < 4; m++)
#pragma unroll
        for (int n = 0; n < 4; n++)
          acc[m][n] = __builtin_amdgcn_mfma_f32_16x16x32_bf16(af[m], bfr[n], acc[m][n], 0, 0, 0);
    }
    __syncthreads();
  }

  // epilogue: C/D layout col = lane&15, row = (lane>>4)*4 + j
  int c0 = lane & 15;
#pragma unroll
  for (int m = 0; m < 4; m++) {
    int rbase = wm * 64 + m * 16 + (lane >> 4) * 4;
#pragma unroll
    for (int j = 0; j < 4; j++) {
      int rglob = row0 + rbase + j;
      if (GELU_STORE) {
#pragma unroll
        for (int n = 0; n < 4; n++) {
          float v = acc[m][n][j];
          float gv = 0.5f * v * (1.0f + erff(v * 0.70710678118654752f));
          hidden[(size_t)rglob * NDIM + n0 + wn * 64 + n * 16 + c0] = (bf16)gv;
        }
      } else {
        int p = perm[rglob];
        if (p >= 0) {
          float w = wt[rglob];
#pragma unroll
          for (int n = 0; n < 4; n++)
            atomicAdd(&out[(size_t)p * DMODEL + n0 + wn * 64 + n * 16 + c0],
                      w * acc[m][n][j]);
        }
      }
    }
  }
}

// ---------------- host ----------------
extern "C" void kernel_launch(void* const* d_in, const int* in_sizes, int n_in,
                              void* d_out, int out_size, void* d_ws, size_t ws_size,
                              hipStream_t stream)
{
  const float* x    = (const float*)d_in[0];
  const float* gw   = (const float*)d_in[1];
  const float* w1   = (const float*)d_in[2];
  const float* w2   = (const float*)d_in[3];
  const float* bias = (const float*)d_in[4];
  float* out = (float*)d_out;

  char* ws = (char*)d_ws;
  size_t o = 0;
  auto alloc = [&](size_t bytes) {
    void* p = ws + o;
    o = (o + bytes + 255) & ~(size_t)255;
    return p;
  };
  bf16*  xb     = (bf16*) alloc((size_t)T_TOKENS * DMODEL * 2);
  bf16*  w1t    = (bf16*) alloc((size_t)NEXP * HDIM * DMODEL * 2);   // [E][H][D]
  bf16*  w2t    = (bf16*) alloc((size_t)NEXP * DMODEL * HDIM * 2);   // [E][D][H]
  bf16*  hidden = (bf16*) alloc((size_t)MAXROWS * HDIM * 2);
  int*   perm   = (int*)  alloc((size_t)MAXROWS * 4);
  float* wt     = (float*)alloc((size_t)MAXROWS * 4);
  int*   es     = (int*)  alloc((size_t)2 * T_TOKENS * 4);
  float* wsv    = (float*)alloc((size_t)2 * T_TOKENS * 4);
  int*   counts = (int*)  alloc(64);
  int*   offs   = (int*)  alloc(64);
  int*   cursor = (int*)  alloc(64);

  hipMemsetAsync(counts, 0, 64, stream);
  hipMemsetAsync(perm, 0xFF, (size_t)MAXROWS * 4, stream);

  router_kernel<<<T_TOKENS / 4, 256, 0, stream>>>(x, gw, xb, es, wsv, counts);
  offsets_kernel<<<1, 64, 0, stream>>>(counts, offs, cursor);
  assign_kernel<<<T_TOKENS / 256, 256, 0, stream>>>(es, wsv, offs, cursor, perm, wt);

  // w1 [E][D][H] -> w1t [E][H][D]
  transpose_cvt_kernel<<<dim3(HDIM / 64, DMODEL / 64, NEXP), 256, 0, stream>>>(w1, w1t, DMODEL, HDIM);
  // w2 [E][H][D] -> w2t [E][D][H]
  transpose_cvt_kernel<<<dim3(DMODEL / 64, HDIM / 64, NEXP), 256, 0, stream>>>(w2, w2t, HDIM, DMODEL);

  out_init_kernel<<<(T_TOKENS * DMODEL) / 256, 256, 0, stream>>>(out, bias);

  moe_gemm_kernel<DMODEL, HDIM, true><<<dim3(MTILES, HDIM / BN), 256, 0, stream>>>(
      xb, w1t, hidden, nullptr, perm, wt, offs);
  moe_gemm_kernel<HDIM, DMODEL, false><<<dim3(MTILES, DMODEL / BN), 256, 0, stream>>>(
      hidden, w2t, nullptr, out, perm, wt, offs);
}